// Round 18
// baseline (25.201 us; speedup 1.0000x reference)
//
#include <hip/hip_runtime.h>
#include <math.h>

// ---------------- problem constants ----------------
#define LHALF   20          // L = M//2, M = 41
#define HDIM    175         // number of (m,n) index pairs, verified below
#define BATCH   65536
#define SLOPE   0.01f

#define BPB     128         // batch elems per block (2 per lane)
#define BLOCK   512         // 8 waves; waves split the h-range
#define NWAVE   8
#define HPW     22          // ceil(175/8)
#define XROW    1040        // bytes per i-row: 128 quads * 8B + 16B pad
#define NGMAX   48          // >= number of non-empty m-groups (+1 dummy)

typedef _Float16 h2_t __attribute__((ext_vector_type(2)));

// ---------------- compile-time index table ----------------
constexpr int count_idx() {
    int k = 0;
    for (int m = -LHALF; m <= LHALF; ++m)
        for (int n = m; n <= LHALF; ++n) {
            int mn = m * n; if (mn < 0) mn = -mn;
            int s  = m + n; if (s  < 0) s  = -s;
            if (mn <= LHALF && s <= LHALF) ++k;
        }
    return k;
}
static_assert(count_idx() == HDIM, "HDIM mismatch with reference enumeration");

// m-groups: consecutive h runs sharing m (n contiguous within each run).
struct GrpTab {
    int endh[NGMAX];    // exclusive end h of group g
    int em  [NGMAX];    // byte offset of Em row (LHALF+m)
    int en0 [NGMAX];    // byte offset of En row at group start (LHALF+n0)
    int emn0[NGMAX];    // byte offset of Emn row at group start (LHALF+m+n0)
    int ng;
    unsigned char sym2[HDIM];
};

constexpr GrpTab make_grp() {
    GrpTab t{};
    int g = -1, h = 0, prev_m = -1000;
    for (int m = -LHALF; m <= LHALF; ++m)
        for (int n = m; n <= LHALF; ++n) {
            int mn = m * n; if (mn < 0) mn = -mn;
            int s  = m + n; if (s  < 0) s  = -s;
            if (mn <= LHALF && s <= LHALF) {
                if (m != prev_m) {
                    ++g;
                    t.em[g]   = (LHALF + m)     * XROW;
                    t.en0[g]  = (LHALF + n)     * XROW;
                    t.emn0[g] = (LHALF + m + n) * XROW;
                    prev_m = m;
                }
                t.endh[g] = h + 1;
                t.sym2[h] = (m != n) ? 1 : 0;
                ++h;
            }
        }
    t.ng = g + 1;
    // dummy tail entry (read after the last flush; must be valid offsets)
    t.endh[g + 1] = HDIM + 1000;
    t.em[g + 1] = 0; t.en0[g + 1] = 0; t.emn0[g + 1] = 0;
    return t;
}

constexpr GrpTab GT = make_grp();
static_assert(GT.ng + 1 <= NGMAX, "NGMAX too small");

// per-wave initial state at hBeg = wv*HPW
struct WaveInit { int g; int endh; int em; int en; int emn; };

constexpr WaveInit winit_for(int hBeg) {
    WaveInit w{};
    int gs = 0;   // start h of group g
    for (int g = 0; g < GT.ng; ++g) {
        if (hBeg < GT.endh[g]) {
            w.g    = g;
            w.endh = GT.endh[g];
            w.em   = GT.em[g];
            w.en   = GT.en0[g]  + (hBeg - gs) * XROW;
            w.emn  = GT.emn0[g] + (hBeg - gs) * XROW;
            return w;
        }
        gs = GT.endh[g];
    }
    return w;
}

struct WInitArr { WaveInit w[NWAVE]; };
constexpr WInitArr make_winit() {
    WInitArr a{};
    for (int v = 0; v < NWAVE; ++v) a.w[v] = winit_for(v * HPW);
    return a;
}
__constant__ WInitArr g_winit = make_winit();
__constant__ GrpTab   g_gt    = GT;

__device__ __forceinline__ float lrelu(float v) {
    return v > 0.0f ? v : SLOPE * v;
}

// ---- f16 helpers ----
__device__ __forceinline__ float fdot2u(unsigned int a, unsigned int b, float c) {
#if __has_builtin(__builtin_amdgcn_fdot2)
    return __builtin_amdgcn_fdot2(__builtin_bit_cast(h2_t, a),
                                  __builtin_bit_cast(h2_t, b), c, false);
#else
    h2_t ha = __builtin_bit_cast(h2_t, a), hb = __builtin_bit_cast(h2_t, b);
    return c + (float)ha[0] * (float)hb[0] + (float)ha[1] * (float)hb[1];
#endif
}
// dot2(a, (w.lo, -w.hi)) + c  -- real part vs plain (wr,wi) weight word.
// h2 shuffle+neg form so the backend can fold into VOP3P neg_hi (R17: ~free).
__device__ __forceinline__ float fdot2_wc(unsigned int a, unsigned int w, float c) {
    h2_t hw = __builtin_bit_cast(h2_t, w);
    h2_t m;
    m[0] =  hw[0];
    m[1] = -hw[1];
#if __has_builtin(__builtin_amdgcn_fdot2)
    return __builtin_amdgcn_fdot2(__builtin_bit_cast(h2_t, a), m, c, false);
#else
    h2_t ha = __builtin_bit_cast(h2_t, a);
    return c + (float)ha[0] * (float)m[0] + (float)ha[1] * (float)m[1];
#endif
}
// dot2(a, (w.hi, w.lo)) + c  -- imag part (half-swap; folds into op_sel).
__device__ __forceinline__ float fdot2_ws(unsigned int a, unsigned int w, float c) {
    h2_t hw = __builtin_bit_cast(h2_t, w);
    h2_t m;
    m[0] = hw[1];
    m[1] = hw[0];
#if __has_builtin(__builtin_amdgcn_fdot2)
    return __builtin_amdgcn_fdot2(__builtin_bit_cast(h2_t, a), m, c, false);
#else
    h2_t ha = __builtin_bit_cast(h2_t, a);
    return c + (float)ha[0] * (float)m[0] + (float)ha[1] * (float)m[1];
#endif
}
__device__ __forceinline__ unsigned int pk_h2(float a, float b) {
#if __has_builtin(__builtin_amdgcn_cvt_pkrtz)
    auto h = __builtin_amdgcn_cvt_pkrtz(a, b);   // __fp16 ext_vector_type(2)
    return __builtin_bit_cast(unsigned int, h);
#else
    h2_t h; h[0] = (_Float16)a; h[1] = (_Float16)b;
    return __builtin_bit_cast(unsigned int, h);
#endif
}
__device__ __forceinline__ float h_lo(unsigned int u) {
    return (float)__builtin_bit_cast(h2_t, u)[0];
}
__device__ __forceinline__ float h_hi(unsigned int u) {
    return (float)__builtin_bit_cast(h2_t, u)[1];
}
// (im, -re) for the conjugate cross term (proven R14 integer form)
__device__ __forceinline__ unsigned int swneg(unsigned int u) {
    return ((u >> 16) | (u << 16)) ^ 0x8000u;
}

// ---------------- kernel ----------------
__global__ __launch_bounds__(BLOCK, 4) void eqpbcnn_kernel(
    const float* __restrict__ x_real, const float* __restrict__ x_imag,
    const float* __restrict__ task,
    const float* __restrict__ W1r, const float* __restrict__ W1i,
    const float* __restrict__ W2r, const float* __restrict__ W2i,
    const float* __restrict__ W3r, const float* __restrict__ W3i,
    float* __restrict__ out)
{
    // x rows: 41 * 1040 B = 42.6 KB; after the h-loop this region is reused
    // for the merge buffer (8 waves * 8 k * 128 b * 4 B = 32 KB <= 42.6 KB).
    __shared__ __align__(16) char  xs[41 * XROW];
    __shared__ __align__(16) uint4 pk1[HDIM];          // 2.8 KB raw (wr,wi) f16 pairs
    __shared__ __align__(16) int4  grpT[NGMAX];        // 768 B group table
    __shared__ float2 w2s[2 * 10 * 2];
    __shared__ float2 w3s[2 * 10];

    static_assert(NWAVE * 8 * BPB * 4 <= 41 * XROW, "merge buffer must fit in xs");

    const int t  = threadIdx.x;
    const int b0 = blockIdx.x * BPB;
    const int ln = t & 63;
    const int wv = t >> 6;          // wave id 0..7

    // ---- stage x: coalesced float2 loads; f16 quad writes ----
    {
        const float2* xr2 = reinterpret_cast<const float2*>(x_real) + (size_t)b0 * 41;
        const float2* xi2 = reinterpret_cast<const float2*>(x_imag) + (size_t)b0 * 41;
        for (int f = t; f < BPB * 41; f += BLOCK) {
            float2 r2 = xr2[f];
            float2 i2 = xi2[f];
            int bl = f / 41;            // magic div
            int i  = f - bl * 41;
            uint2 q;
            q.x = pk_h2(r2.x, i2.x);    // mode0 (re, im)
            q.y = pk_h2(r2.y, i2.y);    // mode1 (re, im)
            *reinterpret_cast<uint2*>(xs + i * XROW + bl * 8) = q;
        }
    }
    // ---- build pk rows: raw f16 (wr,wi) pairs (sym folded), 16 B per h ----
    if (t < HDIM) {
        float sym = g_gt.sym2[t] ? 2.0f : 1.0f;
        uint4 w;
        w.x = pk_h2(W1r[0 * HDIM + t] * sym, W1i[0 * HDIM + t] * sym);  // p0 o0
        w.y = pk_h2(W1r[1 * HDIM + t] * sym, W1i[1 * HDIM + t] * sym);  // p0 o1
        w.z = pk_h2(W1r[2 * HDIM + t] * sym, W1i[2 * HDIM + t] * sym);  // p1 o0
        w.w = pk_h2(W1r[3 * HDIM + t] * sym, W1i[3 * HDIM + t] * sym);  // p1 o1
        pk1[t] = w;
    }
    // ---- group table ----
    if (t >= 256 && t < 256 + NGMAX) {
        int g = t - 256;
        grpT[g] = make_int4(g_gt.endh[g], g_gt.em[g], g_gt.en0[g], g_gt.emn0[g]);
    }
    if (t >= 320 && t < 320 + 40)
        w2s[t - 320] = make_float2(W2r[t - 320], W2i[t - 320]);
    if (t >= 384 && t < 384 + 20)
        w3s[t - 384] = make_float2(W3r[t - 384], W3i[t - 384]);
    __syncthreads();

    // ---- h-loop: 2 batches per lane; group-hoisted Em; ptr-incremented rows ----
    float GA[8] = {0,0,0,0,0,0,0,0}, GB[8] = {0,0,0,0,0,0,0,0};
    float aA[8] = {0,0,0,0,0,0,0,0}, aB[8] = {0,0,0,0,0,0,0,0};
    const char* xlane = xs + ln * 16;       // batches 2ln, 2ln+1 adjacent

    WaveInit wi = g_winit.w[wv];
    int g      = wi.g;
    int endh   = wi.endh;
    int em_off = wi.em;
    const char* pn  = xlane + wi.en;
    const char* pmn = xlane + wi.emn;

    const int hBeg = wv * HPW;
    const int hEnd = (hBeg + HPW < HDIM) ? hBeg + HPW : HDIM;

    for (int h = hBeg; h < hEnd; ++h) {
        uint4 cw = pk1[h];                               // ONE broadcast b128
        uint4 en  = *reinterpret_cast<const uint4*>(pn);   pn  += XROW;
        uint4 emn = *reinterpret_cast<const uint4*>(pmn);  pmn += XROW;

        // A = sum over modes of En * conj(Emn), two batches in parallel
        float arA = fdot2u(en.y, emn.y, fdot2u(en.x, emn.x, 0.f));
        float aiA = fdot2u(en.y, swneg(emn.y), fdot2u(en.x, swneg(emn.x), 0.f));
        float arB = fdot2u(en.w, emn.w, fdot2u(en.z, emn.z, 0.f));
        float aiB = fdot2u(en.w, swneg(emn.w), fdot2u(en.z, swneg(emn.z), 0.f));
        unsigned int a2A = pk_h2(arA, aiA);
        unsigned int a2B = pk_h2(arB, aiB);

        // G[p][o] += A * W1'[p][o][h]   (re: wc-form, im: ws-form, from raw pairs)
        GA[0] = fdot2_wc(a2A, cw.x, GA[0]);  GA[1] = fdot2_ws(a2A, cw.x, GA[1]);
        GA[2] = fdot2_wc(a2A, cw.y, GA[2]);  GA[3] = fdot2_ws(a2A, cw.y, GA[3]);
        GA[4] = fdot2_wc(a2A, cw.z, GA[4]);  GA[5] = fdot2_ws(a2A, cw.z, GA[5]);
        GA[6] = fdot2_wc(a2A, cw.w, GA[6]);  GA[7] = fdot2_ws(a2A, cw.w, GA[7]);
        GB[0] = fdot2_wc(a2B, cw.x, GB[0]);  GB[1] = fdot2_ws(a2B, cw.x, GB[1]);
        GB[2] = fdot2_wc(a2B, cw.y, GB[2]);  GB[3] = fdot2_ws(a2B, cw.y, GB[3]);
        GB[4] = fdot2_wc(a2B, cw.z, GB[4]);  GB[5] = fdot2_ws(a2B, cw.z, GB[5]);
        GB[6] = fdot2_wc(a2B, cw.w, GB[6]);  GB[7] = fdot2_ws(a2B, cw.w, GB[7]);

        if (h + 1 == endh) {            // wave-uniform -> scalar branch
            // flush: acc[p][o] += Em[p] * G[p][o]
            uint4 em = *reinterpret_cast<const uint4*>(xlane + em_off);
            float e0, e1;
            e0 = h_lo(em.x); e1 = h_hi(em.x);
            aA[0] += e0 * GA[0] - e1 * GA[1];  aA[1] += e0 * GA[1] + e1 * GA[0];
            aA[2] += e0 * GA[2] - e1 * GA[3];  aA[3] += e0 * GA[3] + e1 * GA[2];
            e0 = h_lo(em.y); e1 = h_hi(em.y);
            aA[4] += e0 * GA[4] - e1 * GA[5];  aA[5] += e0 * GA[5] + e1 * GA[4];
            aA[6] += e0 * GA[6] - e1 * GA[7];  aA[7] += e0 * GA[7] + e1 * GA[6];
            e0 = h_lo(em.z); e1 = h_hi(em.z);
            aB[0] += e0 * GB[0] - e1 * GB[1];  aB[1] += e0 * GB[1] + e1 * GB[0];
            aB[2] += e0 * GB[2] - e1 * GB[3];  aB[3] += e0 * GB[3] + e1 * GB[2];
            e0 = h_lo(em.w); e1 = h_hi(em.w);
            aB[4] += e0 * GB[4] - e1 * GB[5];  aB[5] += e0 * GB[5] + e1 * GB[4];
            aB[6] += e0 * GB[6] - e1 * GB[7];  aB[7] += e0 * GB[7] + e1 * GB[6];
            #pragma unroll
            for (int k = 0; k < 8; ++k) { GA[k] = 0.f; GB[k] = 0.f; }
            ++g;
            int4 e = grpT[g];
            endh = e.x; em_off = e.y;
            pn  = xlane + e.z;
            pmn = xlane + e.w;
        }
    }
    // final flush (adds 0 if the wave ended exactly on a group boundary)
    {
        uint4 em = *reinterpret_cast<const uint4*>(xlane + em_off);
        float e0, e1;
        e0 = h_lo(em.x); e1 = h_hi(em.x);
        aA[0] += e0 * GA[0] - e1 * GA[1];  aA[1] += e0 * GA[1] + e1 * GA[0];
        aA[2] += e0 * GA[2] - e1 * GA[3];  aA[3] += e0 * GA[3] + e1 * GA[2];
        e0 = h_lo(em.y); e1 = h_hi(em.y);
        aA[4] += e0 * GA[4] - e1 * GA[5];  aA[5] += e0 * GA[5] + e1 * GA[4];
        aA[6] += e0 * GA[6] - e1 * GA[7];  aA[7] += e0 * GA[7] + e1 * GA[6];
        e0 = h_lo(em.z); e1 = h_hi(em.z);
        aB[0] += e0 * GB[0] - e1 * GB[1];  aB[1] += e0 * GB[1] + e1 * GB[0];
        aB[2] += e0 * GB[2] - e1 * GB[3];  aB[3] += e0 * GB[3] + e1 * GB[2];
        e0 = h_lo(em.w); e1 = h_hi(em.w);
        aB[4] += e0 * GB[4] - e1 * GB[5];  aB[5] += e0 * GB[5] + e1 * GB[4];
        aB[6] += e0 * GB[6] - e1 * GB[7];  aB[7] += e0 * GB[7] + e1 * GB[6];
    }

    // ---- all x reads done; merge buffer aliases xs ----
    __syncthreads();
    {
        float* mrgF = reinterpret_cast<float*>(xs) + wv * (8 * BPB);
        #pragma unroll
        for (int k = 0; k < 8; ++k)
            *reinterpret_cast<float2*>(&mrgF[k * BPB + 2 * ln]) =
                make_float2(aA[k], aB[k]);
    }
    __syncthreads();
    // ---- parallel merge: 1024 slots over 512 threads (2 each) ----
    {
        float* mrgF = reinterpret_cast<float*>(xs);
        #pragma unroll
        for (int s = 0; s < 2; ++s) {
            int slot = t + s * BLOCK;       // slot = k*128 + b
            float sum = 0.f;
            #pragma unroll
            for (int w = 0; w < NWAVE; ++w)
                sum += mrgF[w * (8 * BPB) + slot];
            mrgF[slot] = sum;               // in-place region w=0
        }
    }
    __syncthreads();

    // ---- MLP tail: one thread per batch elem ----
    if (t < BPB) {
        const float* accF = reinterpret_cast<const float*>(xs);
        float h1r[2][2], h1i[2][2];
        #pragma unroll
        for (int p = 0; p < 2; ++p)
            #pragma unroll
            for (int o = 0; o < 2; ++o) {
                h1r[p][o] = lrelu(accF[((p * 2 + o) * 2 + 0) * BPB + t]);
                h1i[p][o] = lrelu(accF[((p * 2 + o) * 2 + 1) * BPB + t]);
            }

        float Er[2], Ei[2];
        #pragma unroll
        for (int p = 0; p < 2; ++p) {
            float er = 0.f, ei = 0.f;
            #pragma unroll
            for (int q = 0; q < 10; ++q) {
                float hr = 0.f, hi = 0.f;
                #pragma unroll
                for (int o = 0; o < 2; ++o) {
                    float2 w = w2s[(p * 10 + q) * 2 + o];
                    hr += h1r[p][o] * w.x - h1i[p][o] * w.y;
                    hi += h1r[p][o] * w.y + h1i[p][o] * w.x;
                }
                hr = lrelu(hr); hi = lrelu(hi);
                float2 w3 = w3s[p * 10 + q];
                er += hr * w3.x - hi * w3.y;
                ei += hr * w3.y + hi * w3.x;
            }
            Er[p] = er; Ei[p] = ei;
        }

        int gb = b0 + t;
        float P = exp10f(task[gb * 4] * 0.1f) * 0.5f;   // 10^(ti/10) / NMODES

        // exact fp32 x[:,L,:] re-read from global (carrier term exact)
        const float* xrL = x_real + (size_t)gb * 82 + LHALF * 2;
        const float* xiL = x_imag + (size_t)gb * 82 + LHALF * 2;

        float4 o4;
        o4.x = xrL[0] + Er[0] * P;
        o4.y = xiL[0] + Ei[0] * P;
        o4.z = xrL[1] + Er[1] * P;
        o4.w = xiL[1] + Ei[1] * P;
        reinterpret_cast<float4*>(out)[gb] = o4;
    }
}

// ---------------- launch ----------------
extern "C" void kernel_launch(void* const* d_in, const int* in_sizes, int n_in,
                              void* d_out, int out_size, void* d_ws, size_t ws_size,
                              hipStream_t stream) {
    const float* x_real = (const float*)d_in[0];
    const float* x_imag = (const float*)d_in[1];
    const float* task   = (const float*)d_in[2];
    const float* W1r    = (const float*)d_in[3];
    const float* W1i    = (const float*)d_in[4];
    const float* W2r    = (const float*)d_in[5];
    const float* W2i    = (const float*)d_in[6];
    const float* W3r    = (const float*)d_in[7];
    const float* W3i    = (const float*)d_in[8];
    float* out = (float*)d_out;

    dim3 grid(BATCH / BPB);     // 512 blocks
    dim3 block(BLOCK);
    hipLaunchKernelGGL(eqpbcnn_kernel, grid, block, 0, stream,
                       x_real, x_imag, task, W1r, W1i, W2r, W2i, W3r, W3i, out);
}

// Round 19
// 23.685 us; speedup vs baseline: 1.0640x; 1.0640x over previous
//
#include <hip/hip_runtime.h>
#include <math.h>

// ---------------- problem constants ----------------
#define LHALF   20          // L = M//2, M = 41
#define HDIM    175         // number of (m,n) index pairs, verified below
#define BATCH   65536
#define SLOPE   0.01f

#define BPB     128         // batch elems per block (2 per lane)
#define BLOCK   512         // 8 waves; waves split the h-range
#define NWAVE   8
#define HPW     22          // ceil(175/8)
#define XROW    1040        // bytes per i-row: 128 quads * 8B + 16B pad
#define NGMAX   48          // >= number of non-empty m-groups (+1 dummy)

typedef _Float16 h2_t __attribute__((ext_vector_type(2)));

// ---------------- compile-time index table ----------------
constexpr int count_idx() {
    int k = 0;
    for (int m = -LHALF; m <= LHALF; ++m)
        for (int n = m; n <= LHALF; ++n) {
            int mn = m * n; if (mn < 0) mn = -mn;
            int s  = m + n; if (s  < 0) s  = -s;
            if (mn <= LHALF && s <= LHALF) ++k;
        }
    return k;
}
static_assert(count_idx() == HDIM, "HDIM mismatch with reference enumeration");

// m-groups: consecutive h runs sharing m (n contiguous within each run).
struct GrpTab {
    int endh[NGMAX];    // exclusive end h of group g
    int em  [NGMAX];    // byte offset of Em row (LHALF+m)
    int en0 [NGMAX];    // byte offset of En row at group start (LHALF+n0)
    int emn0[NGMAX];    // byte offset of Emn row at group start (LHALF+m+n0)
    int ng;
    unsigned char sym2[HDIM];
};

constexpr GrpTab make_grp() {
    GrpTab t{};
    int g = -1, h = 0, prev_m = -1000;
    for (int m = -LHALF; m <= LHALF; ++m)
        for (int n = m; n <= LHALF; ++n) {
            int mn = m * n; if (mn < 0) mn = -mn;
            int s  = m + n; if (s  < 0) s  = -s;
            if (mn <= LHALF && s <= LHALF) {
                if (m != prev_m) {
                    ++g;
                    t.em[g]   = (LHALF + m)     * XROW;
                    t.en0[g]  = (LHALF + n)     * XROW;
                    t.emn0[g] = (LHALF + m + n) * XROW;
                    prev_m = m;
                }
                t.endh[g] = h + 1;
                t.sym2[h] = (m != n) ? 1 : 0;
                ++h;
            }
        }
    t.ng = g + 1;
    // dummy tail entry (read after the last flush; must be valid offsets)
    t.endh[g + 1] = HDIM + 1000;
    t.em[g + 1] = 0; t.en0[g + 1] = 0; t.emn0[g + 1] = 0;
    return t;
}

constexpr GrpTab GT = make_grp();
static_assert(GT.ng + 1 <= NGMAX, "NGMAX too small");

// per-wave initial state at hBeg = wv*HPW
struct WaveInit { int g; int endh; int em; int en; int emn; };

constexpr WaveInit winit_for(int hBeg) {
    WaveInit w{};
    int gs = 0;   // start h of group g
    for (int g = 0; g < GT.ng; ++g) {
        if (hBeg < GT.endh[g]) {
            w.g    = g;
            w.endh = GT.endh[g];
            w.em   = GT.em[g];
            w.en   = GT.en0[g]  + (hBeg - gs) * XROW;
            w.emn  = GT.emn0[g] + (hBeg - gs) * XROW;
            return w;
        }
        gs = GT.endh[g];
    }
    return w;
}

struct WInitArr { WaveInit w[NWAVE]; };
constexpr WInitArr make_winit() {
    WInitArr a{};
    for (int v = 0; v < NWAVE; ++v) a.w[v] = winit_for(v * HPW);
    return a;
}
__constant__ WInitArr g_winit = make_winit();
__constant__ GrpTab   g_gt    = GT;

__device__ __forceinline__ float lrelu(float v) {
    return v > 0.0f ? v : SLOPE * v;
}

// ---- f16 helpers ----
__device__ __forceinline__ float fdot2u(unsigned int a, unsigned int b, float c) {
#if __has_builtin(__builtin_amdgcn_fdot2)
    return __builtin_amdgcn_fdot2(__builtin_bit_cast(h2_t, a),
                                  __builtin_bit_cast(h2_t, b), c, false);
#else
    h2_t ha = __builtin_bit_cast(h2_t, a), hb = __builtin_bit_cast(h2_t, b);
    return c + (float)ha[0] * (float)hb[0] + (float)ha[1] * (float)hb[1];
#endif
}
__device__ __forceinline__ unsigned int pk_h2(float a, float b) {
#if __has_builtin(__builtin_amdgcn_cvt_pkrtz)
    auto h = __builtin_amdgcn_cvt_pkrtz(a, b);   // __fp16 ext_vector_type(2)
    return __builtin_bit_cast(unsigned int, h);
#else
    h2_t h; h[0] = (_Float16)a; h[1] = (_Float16)b;
    return __builtin_bit_cast(unsigned int, h);
#endif
}
__device__ __forceinline__ float h_lo(unsigned int u) {
    return (float)__builtin_bit_cast(h2_t, u)[0];
}
__device__ __forceinline__ float h_hi(unsigned int u) {
    return (float)__builtin_bit_cast(h2_t, u)[1];
}
// (im, -re) for the conjugate cross term
__device__ __forceinline__ unsigned int swneg(unsigned int u) {
    return ((u >> 16) | (u << 16)) ^ 0x8000u;
}

// ---------------- kernel ----------------
__global__ __launch_bounds__(BLOCK, 4) void eqpbcnn_kernel(
    const float* __restrict__ x_real, const float* __restrict__ x_imag,
    const float* __restrict__ task,
    const float* __restrict__ W1r, const float* __restrict__ W1i,
    const float* __restrict__ W2r, const float* __restrict__ W2i,
    const float* __restrict__ W3r, const float* __restrict__ W3i,
    float* __restrict__ out)
{
    // x rows: 41 * 1040 B = 42.6 KB; after the h-loop this region is reused
    // for the merge buffer (8 waves * 8 k * 128 b * 4 B = 32 KB <= 42.6 KB).
    __shared__ __align__(16) char  xs[41 * XROW];
    __shared__ __align__(16) uint4 pk2[HDIM * 2];      // 5.6 KB weight combos
    __shared__ __align__(16) int4  grpT[NGMAX];        // 768 B group table
    __shared__ float2 w2s[2 * 10 * 2];
    __shared__ float2 w3s[2 * 10];

    static_assert(NWAVE * 8 * BPB * 4 <= 41 * XROW, "merge buffer must fit in xs");

    const int t  = threadIdx.x;
    const int b0 = blockIdx.x * BPB;
    const int ln = t & 63;
    const int wv = t >> 6;          // wave id 0..7

    // ---- stage x: coalesced float2 loads; f16 quad writes ----
    {
        const float2* xr2 = reinterpret_cast<const float2*>(x_real) + (size_t)b0 * 41;
        const float2* xi2 = reinterpret_cast<const float2*>(x_imag) + (size_t)b0 * 41;
        for (int f = t; f < BPB * 41; f += BLOCK) {
            float2 r2 = xr2[f];
            float2 i2 = xi2[f];
            int bl = f / 41;            // magic div
            int i  = f - bl * 41;
            uint2 q;
            q.x = pk_h2(r2.x, i2.x);    // mode0 (re, im)
            q.y = pk_h2(r2.y, i2.y);    // mode1 (re, im)
            *reinterpret_cast<uint2*>(xs + i * XROW + bl * 8) = q;
        }
    }
    // ---- build pk rows: f16 weight combos (sym folded), 32 B per h ----
    if (t < HDIM) {
        float sym = g_gt.sym2[t] ? 2.0f : 1.0f;
        float wr0 = W1r[0 * HDIM + t] * sym, wi0 = W1i[0 * HDIM + t] * sym;
        float wr1 = W1r[1 * HDIM + t] * sym, wi1 = W1i[1 * HDIM + t] * sym;
        float wr2 = W1r[2 * HDIM + t] * sym, wi2 = W1i[2 * HDIM + t] * sym;
        float wr3 = W1r[3 * HDIM + t] * sym, wi3 = W1i[3 * HDIM + t] * sym;
        uint4 cA, cB;
        cA.x = pk_h2(wr0, -wi0);  cA.y = pk_h2(wi0, wr0);
        cA.z = pk_h2(wr1, -wi1);  cA.w = pk_h2(wi1, wr1);
        cB.x = pk_h2(wr2, -wi2);  cB.y = pk_h2(wi2, wr2);
        cB.z = pk_h2(wr3, -wi3);  cB.w = pk_h2(wi3, wr3);
        pk2[2 * t]     = cA;
        pk2[2 * t + 1] = cB;
    }
    // ---- group table ----
    if (t >= 256 && t < 256 + NGMAX) {
        int g = t - 256;
        grpT[g] = make_int4(g_gt.endh[g], g_gt.em[g], g_gt.en0[g], g_gt.emn0[g]);
    }
    if (t >= 320 && t < 320 + 40)
        w2s[t - 320] = make_float2(W2r[t - 320], W2i[t - 320]);
    if (t >= 384 && t < 384 + 20)
        w3s[t - 384] = make_float2(W3r[t - 384], W3i[t - 384]);
    __syncthreads();

    // ---- h-loop: 2 batches per lane; group-hoisted Em; ptr-incremented rows ----
    float GA[8] = {0,0,0,0,0,0,0,0}, GB[8] = {0,0,0,0,0,0,0,0};
    float aA[8] = {0,0,0,0,0,0,0,0}, aB[8] = {0,0,0,0,0,0,0,0};
    const char* xlane = xs + ln * 16;       // batches 2ln, 2ln+1 adjacent

    WaveInit wi = g_winit.w[wv];
    int g      = wi.g;
    int endh   = wi.endh;
    int em_off = wi.em;
    const char* pn  = xlane + wi.en;
    const char* pmn = xlane + wi.emn;

    const int hBeg = wv * HPW;
    const int hEnd = (hBeg + HPW < HDIM) ? hBeg + HPW : HDIM;

    for (int h = hBeg; h < hEnd; ++h) {
        uint4 cA = pk2[2 * h];                           // broadcast b128
        uint4 cB = pk2[2 * h + 1];                       // broadcast b128
        uint4 en  = *reinterpret_cast<const uint4*>(pn);   pn  += XROW;
        uint4 emn = *reinterpret_cast<const uint4*>(pmn);  pmn += XROW;

        // A = sum over modes of En * conj(Emn), two batches in parallel
        float arA = fdot2u(en.y, emn.y, fdot2u(en.x, emn.x, 0.f));
        float aiA = fdot2u(en.y, swneg(emn.y), fdot2u(en.x, swneg(emn.x), 0.f));
        float arB = fdot2u(en.w, emn.w, fdot2u(en.z, emn.z, 0.f));
        float aiB = fdot2u(en.w, swneg(emn.w), fdot2u(en.z, swneg(emn.z), 0.f));
        unsigned int a2A = pk_h2(arA, aiA);
        unsigned int a2B = pk_h2(arB, aiB);

        // G[p][o] += A * W1'[p][o][h]
        GA[0] = fdot2u(a2A, cA.x, GA[0]);  GA[1] = fdot2u(a2A, cA.y, GA[1]);
        GA[2] = fdot2u(a2A, cA.z, GA[2]);  GA[3] = fdot2u(a2A, cA.w, GA[3]);
        GA[4] = fdot2u(a2A, cB.x, GA[4]);  GA[5] = fdot2u(a2A, cB.y, GA[5]);
        GA[6] = fdot2u(a2A, cB.z, GA[6]);  GA[7] = fdot2u(a2A, cB.w, GA[7]);
        GB[0] = fdot2u(a2B, cA.x, GB[0]);  GB[1] = fdot2u(a2B, cA.y, GB[1]);
        GB[2] = fdot2u(a2B, cA.z, GB[2]);  GB[3] = fdot2u(a2B, cA.w, GB[3]);
        GB[4] = fdot2u(a2B, cB.x, GB[4]);  GB[5] = fdot2u(a2B, cB.y, GB[5]);
        GB[6] = fdot2u(a2B, cB.z, GB[6]);  GB[7] = fdot2u(a2B, cB.w, GB[7]);

        if (h + 1 == endh) {            // wave-uniform -> scalar branch
            // flush: acc[p][o] += Em[p] * G[p][o]
            uint4 em = *reinterpret_cast<const uint4*>(xlane + em_off);
            float e0, e1;
            e0 = h_lo(em.x); e1 = h_hi(em.x);
            aA[0] += e0 * GA[0] - e1 * GA[1];  aA[1] += e0 * GA[1] + e1 * GA[0];
            aA[2] += e0 * GA[2] - e1 * GA[3];  aA[3] += e0 * GA[3] + e1 * GA[2];
            e0 = h_lo(em.y); e1 = h_hi(em.y);
            aA[4] += e0 * GA[4] - e1 * GA[5];  aA[5] += e0 * GA[5] + e1 * GA[4];
            aA[6] += e0 * GA[6] - e1 * GA[7];  aA[7] += e0 * GA[7] + e1 * GA[6];
            e0 = h_lo(em.z); e1 = h_hi(em.z);
            aB[0] += e0 * GB[0] - e1 * GB[1];  aB[1] += e0 * GB[1] + e1 * GB[0];
            aB[2] += e0 * GB[2] - e1 * GB[3];  aB[3] += e0 * GB[3] + e1 * GB[2];
            e0 = h_lo(em.w); e1 = h_hi(em.w);
            aB[4] += e0 * GB[4] - e1 * GB[5];  aB[5] += e0 * GB[5] + e1 * GB[4];
            aB[6] += e0 * GB[6] - e1 * GB[7];  aB[7] += e0 * GB[7] + e1 * GB[6];
            #pragma unroll
            for (int k = 0; k < 8; ++k) { GA[k] = 0.f; GB[k] = 0.f; }
            ++g;
            int4 e = grpT[g];
            endh = e.x; em_off = e.y;
            pn  = xlane + e.z;
            pmn = xlane + e.w;
        }
    }
    // final flush (adds 0 if the wave ended exactly on a group boundary)
    {
        uint4 em = *reinterpret_cast<const uint4*>(xlane + em_off);
        float e0, e1;
        e0 = h_lo(em.x); e1 = h_hi(em.x);
        aA[0] += e0 * GA[0] - e1 * GA[1];  aA[1] += e0 * GA[1] + e1 * GA[0];
        aA[2] += e0 * GA[2] - e1 * GA[3];  aA[3] += e0 * GA[3] + e1 * GA[2];
        e0 = h_lo(em.y); e1 = h_hi(em.y);
        aA[4] += e0 * GA[4] - e1 * GA[5];  aA[5] += e0 * GA[5] + e1 * GA[4];
        aA[6] += e0 * GA[6] - e1 * GA[7];  aA[7] += e0 * GA[7] + e1 * GA[6];
        e0 = h_lo(em.z); e1 = h_hi(em.z);
        aB[0] += e0 * GB[0] - e1 * GB[1];  aB[1] += e0 * GB[1] + e1 * GB[0];
        aB[2] += e0 * GB[2] - e1 * GB[3];  aB[3] += e0 * GB[3] + e1 * GB[2];
        e0 = h_lo(em.w); e1 = h_hi(em.w);
        aB[4] += e0 * GB[4] - e1 * GB[5];  aB[5] += e0 * GB[5] + e1 * GB[4];
        aB[6] += e0 * GB[6] - e1 * GB[7];  aB[7] += e0 * GB[7] + e1 * GB[6];
    }

    // ---- all x reads done; merge buffer aliases xs ----
    __syncthreads();
    {
        float* mrgF = reinterpret_cast<float*>(xs) + wv * (8 * BPB);
        #pragma unroll
        for (int k = 0; k < 8; ++k)
            *reinterpret_cast<float2*>(&mrgF[k * BPB + 2 * ln]) =
                make_float2(aA[k], aB[k]);
    }
    __syncthreads();
    // ---- parallel merge: 1024 slots over 512 threads (2 each) ----
    {
        float* mrgF = reinterpret_cast<float*>(xs);
        #pragma unroll
        for (int s = 0; s < 2; ++s) {
            int slot = t + s * BLOCK;       // slot = k*128 + b
            float sum = 0.f;
            #pragma unroll
            for (int w = 0; w < NWAVE; ++w)
                sum += mrgF[w * (8 * BPB) + slot];
            mrgF[slot] = sum;               // in-place region w=0
        }
    }
    __syncthreads();

    // ---- MLP tail: one thread per batch elem ----
    if (t < BPB) {
        const float* accF = reinterpret_cast<const float*>(xs);
        float h1r[2][2], h1i[2][2];
        #pragma unroll
        for (int p = 0; p < 2; ++p)
            #pragma unroll
            for (int o = 0; o < 2; ++o) {
                h1r[p][o] = lrelu(accF[((p * 2 + o) * 2 + 0) * BPB + t]);
                h1i[p][o] = lrelu(accF[((p * 2 + o) * 2 + 1) * BPB + t]);
            }

        float Er[2], Ei[2];
        #pragma unroll
        for (int p = 0; p < 2; ++p) {
            float er = 0.f, ei = 0.f;
            #pragma unroll
            for (int q = 0; q < 10; ++q) {
                float hr = 0.f, hi = 0.f;
                #pragma unroll
                for (int o = 0; o < 2; ++o) {
                    float2 w = w2s[(p * 10 + q) * 2 + o];
                    hr += h1r[p][o] * w.x - h1i[p][o] * w.y;
                    hi += h1r[p][o] * w.y + h1i[p][o] * w.x;
                }
                hr = lrelu(hr); hi = lrelu(hi);
                float2 w3 = w3s[p * 10 + q];
                er += hr * w3.x - hi * w3.y;
                ei += hr * w3.y + hi * w3.x;
            }
            Er[p] = er; Ei[p] = ei;
        }

        int gb = b0 + t;
        float P = exp10f(task[gb * 4] * 0.1f) * 0.5f;   // 10^(ti/10) / NMODES

        // exact fp32 x[:,L,:] re-read from global (carrier term exact)
        const float* xrL = x_real + (size_t)gb * 82 + LHALF * 2;
        const float* xiL = x_imag + (size_t)gb * 82 + LHALF * 2;

        float4 o4;
        o4.x = xrL[0] + Er[0] * P;
        o4.y = xiL[0] + Ei[0] * P;
        o4.z = xrL[1] + Er[1] * P;
        o4.w = xiL[1] + Ei[1] * P;
        reinterpret_cast<float4*>(out)[gb] = o4;
    }
}

// ---------------- launch ----------------
extern "C" void kernel_launch(void* const* d_in, const int* in_sizes, int n_in,
                              void* d_out, int out_size, void* d_ws, size_t ws_size,
                              hipStream_t stream) {
    const float* x_real = (const float*)d_in[0];
    const float* x_imag = (const float*)d_in[1];
    const float* task   = (const float*)d_in[2];
    const float* W1r    = (const float*)d_in[3];
    const float* W1i    = (const float*)d_in[4];
    const float* W2r    = (const float*)d_in[5];
    const float* W2i    = (const float*)d_in[6];
    const float* W3r    = (const float*)d_in[7];
    const float* W3i    = (const float*)d_in[8];
    float* out = (float*)d_out;

    dim3 grid(BATCH / BPB);     // 512 blocks
    dim3 block(BLOCK);
    hipLaunchKernelGGL(eqpbcnn_kernel, grid, block, 0, stream,
                       x_real, x_imag, task, W1r, W1i, W2r, W2i, W3r, W3i, out);
}